// Round 15
// baseline (143.822 us; speedup 1.0000x reference)
//
#include <hip/hip_runtime.h>

// Problem constants (from reference)
#define N_NODES 2048
#define C_CH    128
#define NIRR    9
#define E_EL    10
// dslot mapping: 0 -> l0 (d=0), 1..3 -> l1 (d=0..2)

// Symmetrized coupling tables, packed per-role for LDS staging:
// per role r (= dslot): [ us3 165*4 | us2 45*4 (k3 pad0) | us1 9*2 + 2 pad ]
//   role stride 860 floats (3440 B, 16B-aligned); total 3440 floats = 13.76 KB
#define NS3 165
#define NS2 45
#define ROLE_STRIDE 860
#define OFF3 0
#define OFF2 660
#define OFF1 840
#define TAB_FLOATS (4 * ROLE_STRIDE)   // 3440

typedef float pf2 __attribute__((ext_vector_type(2)));

// Compile-time index tables for the flattened symmetric triple loop.
struct Tab {
    unsigned char pairP[NS2], pairQ[NS2];
    unsigned char triPair[NS3], triI[NS3];
};
constexpr Tab makeTab() {
    Tab t{};
    int s2 = 0, s3 = 0;
    for (int p = 0; p < 9; p++)
        for (int q = p; q < 9; q++) {
            t.pairP[s2] = (unsigned char)p;
            t.pairQ[s2] = (unsigned char)q;
            for (int i = q; i < 9; i++) {
                t.triPair[s3] = (unsigned char)s2;
                t.triI[s3] = (unsigned char)i;
                s3++;
            }
            s2++;
        }
    return t;
}
constexpr Tab TAB = makeTab();

// Symmetrize u3/u2/u1 over index-permutation orbits into the packed layout.
__global__ __launch_bounds__(256) void build_sym_kernel(
    const float* __restrict__ u3_l0, const float* __restrict__ u2_l0, const float* __restrict__ u1_l0,
    const float* __restrict__ u3_l1, const float* __restrict__ u2_l1, const float* __restrict__ u1_l1,
    float* __restrict__ tab)
{
    int t = blockIdx.x * 256 + threadIdx.x;
    if (t >= TAB_FLOATS) return;
    int ds = t / ROLE_STRIDE;
    int off = t % ROLE_STRIDE;
    float v = 0.f;
    if (off < OFF2) {
        int s = off >> 2, k = off & 3;
        int pp = 0, qq = 0, ii = 0, cntr = 0;
        for (int p = 0; p < 9; p++)
            for (int q = p; q < 9; q++)
                for (int i = q; i < 9; i++) {
                    if (cntr == s) { pp = p; qq = q; ii = i; }
                    cntr++;
                }
        const float* u = (ds == 0) ? u3_l0 : (u3_l1 + (ds - 1) * 2916);
        int perm[6][3] = {{pp,qq,ii},{pp,ii,qq},{qq,pp,ii},{qq,ii,pp},{ii,pp,qq},{ii,qq,pp}};
        float acc = 0.f;
        #pragma unroll
        for (int j = 0; j < 6; j++)
            acc += u[((perm[j][0] * 9 + perm[j][1]) * 9 + perm[j][2]) * 4 + k];
        float mult = (pp == qq && qq == ii) ? 6.f : ((pp == qq || qq == ii) ? 2.f : 1.f);
        v = acc / mult;
    } else if (off < OFF1) {
        int o2 = off - OFF2;
        int s = o2 >> 2, k = o2 & 3;
        if (k < 3) {
            int pp = 0, qq = 0, cntr = 0;
            for (int p = 0; p < 9; p++)
                for (int q = p; q < 9; q++) {
                    if (cntr == s) { pp = p; qq = q; }
                    cntr++;
                }
            const float* u = (ds == 0) ? u2_l0 : (u2_l1 + (ds - 1) * 243);
            float acc = u[(pp * 9 + qq) * 3 + k] + u[(qq * 9 + pp) * 3 + k];
            v = (pp == qq) ? acc * 0.5f : acc;
        }
    } else {
        int o1 = off - OFF1;
        if (o1 < 18) {
            int p = o1 >> 1, k = o1 & 1;
            const float* u = (ds == 0) ? u1_l0 : (u1_l1 + (ds - 1) * 18);
            v = u[p * 2 + k];
        }
    }
    tab[t] = v;
}

// Fused contraction + o3.Linear + skip. One node per block.
// Block = 512 = 128 c x 4 roles; role r computes dslot r only.
// Table staged in LDS (13.76 KB, trivial copy) and read via wave-uniform
// broadcast ds_read_b128 (conflict-free). Unlike SMEM s_load (out-of-order
// return -> all-or-nothing lgkm drains, the R8-R13 ~45us floor), LDS returns
// in-order so the compiler pipelines reads ahead of the pk_fma stream.
// NOTE: VGPR cap must stay >=128: (512,4) -> 128. R5's 64-cap spilled (14x).
__global__ __launch_bounds__(512, 4) void fused_kernel(
    const float* __restrict__ x, const float* __restrict__ y,
    const float* __restrict__ tab,
    const float* __restrict__ w3_l0, const float* __restrict__ w2_l0, const float* __restrict__ w1_l0,
    const float* __restrict__ w3_l1, const float* __restrict__ w2_l1, const float* __restrict__ w1_l1,
    const float* __restrict__ lw0, const float* __restrict__ lw1,
    const float* __restrict__ sc, float* __restrict__ out)
{
    __shared__ float ltab[TAB_FLOATS];   // 13760 B
    __shared__ float fs[4][132];         //  2112 B
    int tid = threadIdx.x;
    int c = tid & 127;
    int r = __builtin_amdgcn_readfirstlane(tid >> 7);   // role == dslot, wave-uniform
    int b = blockIdx.x;

    // stage table into LDS (vector copy: 3440 floats = 860 float4)
    {
        const float4* g4 = (const float4*)tab;
        float4* l4 = (float4*)ltab;
        for (int t = tid; t < TAB_FLOATS / 4; t += 512) l4[t] = g4[t];
    }

    int e = 0;
    #pragma unroll
    for (int k = 1; k < E_EL; k++)
        if (y[b * E_EL + k] > 0.5f) e = k;
    e = __builtin_amdgcn_readfirstlane(e);

    float xv[9];
    {
        const float* xp = x + ((size_t)b * C_CH + c) * NIRR;
        #pragma unroll
        for (int i = 0; i < 9; i++) xv[i] = xp[i];
    }

    __syncthreads();

    const float* base = ltab + r * ROLE_STRIDE;
    const float4* T3 = (const float4*)(base + OFF3);   // [s] -> k0..k3
    const float4* T2 = (const float4*)(base + OFF2);   // [pi] -> k0,k1,k2,0
    const pf2*    T1 = (const pf2*)(base + OFF1);      // [p] -> k0,k1

    pf2 G3a = {0.f, 0.f}, G3b = {0.f, 0.f};
    pf2 G2a = {0.f, 0.f};
    float G2c = 0.f;
    pf2 G1v = {0.f, 0.f};

    #pragma unroll
    for (int p = 0; p < 9; p++) {
        pf2 u1v = T1[p];
        pf2 xpv = {xv[p], xv[p]};
        G1v = __builtin_elementwise_fma(u1v, xpv, G1v);
    }

    float pq = 0.f;
    #pragma unroll
    for (int s = 0; s < NS3; s++) {
        const int pi = TAB.triPair[s];
        if (s == 0 || TAB.triPair[s] != TAB.triPair[s - 1]) {
            pq = xv[TAB.pairP[pi]] * xv[TAB.pairQ[pi]];
            float4 u2v = T2[pi];
            pf2 u2ab = {u2v.x, u2v.y};
            pf2 pqv = {pq, pq};
            G2a = __builtin_elementwise_fma(u2ab, pqv, G2a);
            G2c = __builtin_fmaf(u2v.z, pq, G2c);
        }
        float X = pq * xv[TAB.triI[s]];
        float4 u3v = T3[s];
        pf2 ua = {u3v.x, u3v.y};
        pf2 ub = {u3v.z, u3v.w};
        pf2 Xv = {X, X};
        G3a = __builtin_elementwise_fma(ua, Xv, G3a);
        G3b = __builtin_elementwise_fma(ub, Xv, G3b);
    }

    float G3[4] = {G3a.x, G3a.y, G3b.x, G3b.y};
    float G2[3] = {G2a.x, G2a.y, G2c};
    float G1[2] = {G1v.x, G1v.y};

    // element weights (lane c): w3 (E,4,C), w2 (E,3,C), w1 (E,2,C)
    float acc = 0.f;
    if (r == 0) {
        #pragma unroll
        for (int k = 0; k < 4; k++) acc += w3_l0[(e * 4 + k) * 128 + c] * G3[k];
        #pragma unroll
        for (int k = 0; k < 3; k++) acc += w2_l0[(e * 3 + k) * 128 + c] * G2[k];
        #pragma unroll
        for (int k = 0; k < 2; k++) acc += w1_l0[(e * 2 + k) * 128 + c] * G1[k];
    } else {
        #pragma unroll
        for (int k = 0; k < 4; k++) acc += w3_l1[(e * 4 + k) * 128 + c] * G3[k];
        #pragma unroll
        for (int k = 0; k < 3; k++) acc += w2_l1[(e * 3 + k) * 128 + c] * G2[k];
        #pragma unroll
        for (int k = 0; k < 2; k++) acc += w1_l1[(e * 2 + k) * 128 + c] * G1[k];
    }
    fs[r][c] = acc;
    __syncthreads();

    // ---- o3.Linear + skip: threads 0..127 only, 4 contiguous j-cols each ----
    if (tid < 128) {
        int sel, m = 0, j0;
        const float4* W4;
        bool isl0 = (tid < 32);
        if (isl0) { sel = 0; j0 = 4 * tid; W4 = (const float4*)lw0; }
        else {
            int idx = tid - 32;
            m = idx >> 5;
            j0 = 4 * (idx & 31);
            sel = 1 + m;
            W4 = (const float4*)lw1;
        }
        int wbase = j0 >> 2;

        float a0 = 0.f, a1 = 0.f, a2 = 0.f, a3 = 0.f;
        #pragma unroll 4
        for (int ib = 0; ib < 32; ib++) {
            float4 f = *(const float4*)&fs[sel][4 * ib];
            float4 w0 = W4[(4 * ib + 0) * 32 + wbase];
            float4 w1 = W4[(4 * ib + 1) * 32 + wbase];
            float4 w2 = W4[(4 * ib + 2) * 32 + wbase];
            float4 w3 = W4[(4 * ib + 3) * 32 + wbase];
            a0 += f.x * w0.x + f.y * w1.x + f.z * w2.x + f.w * w3.x;
            a1 += f.x * w0.y + f.y * w1.y + f.z * w2.y + f.w * w3.y;
            a2 += f.x * w0.z + f.y * w1.z + f.z * w2.z + f.w * w3.z;
            a3 += f.x * w0.w + f.y * w1.w + f.z * w2.w + f.w * w3.w;
        }

        const float inv_sqrt_c = 0.08838834764831845f;  // 1/sqrt(128)
        if (isl0) {
            size_t o = (size_t)b * 512 + j0;
            float4 s = *(const float4*)(sc + o);
            float4 rr;
            rr.x = a0 * inv_sqrt_c + s.x;
            rr.y = a1 * inv_sqrt_c + s.y;
            rr.z = a2 * inv_sqrt_c + s.z;
            rr.w = a3 * inv_sqrt_c + s.w;
            *(float4*)(out + o) = rr;
        } else {
            float av[4] = {a0, a1, a2, a3};
            #pragma unroll
            for (int jj = 0; jj < 4; jj++) {
                size_t o = (size_t)b * 512 + 128 + 3 * (j0 + jj) + m;
                out[o] = av[jj] * inv_sqrt_c + sc[o];
            }
        }
    }
}

extern "C" void kernel_launch(void* const* d_in, const int* in_sizes, int n_in,
                              void* d_out, int out_size, void* d_ws, size_t ws_size,
                              hipStream_t stream) {
    const float* x     = (const float*)d_in[0];
    const float* y     = (const float*)d_in[1];
    const float* sc    = (const float*)d_in[2];
    const float* u3_l0 = (const float*)d_in[3];
    const float* u2_l0 = (const float*)d_in[4];
    const float* u1_l0 = (const float*)d_in[5];
    const float* w3_l0 = (const float*)d_in[6];
    const float* w2_l0 = (const float*)d_in[7];
    const float* w1_l0 = (const float*)d_in[8];
    const float* u3_l1 = (const float*)d_in[9];
    const float* u2_l1 = (const float*)d_in[10];
    const float* u1_l1 = (const float*)d_in[11];
    const float* w3_l1 = (const float*)d_in[12];
    const float* w2_l1 = (const float*)d_in[13];
    const float* w1_l1 = (const float*)d_in[14];
    const float* lw0   = (const float*)d_in[15];
    const float* lw1   = (const float*)d_in[16];
    float* out = (float*)d_out;

    float* tab = (float*)d_ws;

    build_sym_kernel<<<(TAB_FLOATS + 255) / 256, 256, 0, stream>>>(
        u3_l0, u2_l0, u1_l0, u3_l1, u2_l1, u1_l1, tab);
    fused_kernel<<<N_NODES, 512, 0, stream>>>(
        x, y, tab,
        w3_l0, w2_l0, w1_l0, w3_l1, w2_l1, w1_l1,
        lw0, lw1, sc, out);
}

// Round 16
// 139.938 us; speedup vs baseline: 1.0278x; 1.0278x over previous
//
#include <hip/hip_runtime.h>

// Problem constants (from reference)
#define N_NODES 2048
#define C_CH    128
#define NIRR    9
#define E_EL    10
// dslot mapping: 0 -> l0 (d=0), 1..3 -> l1 (d=0..2)

// Symmetrized coupling tables, role-major (R12 layout, SMEM s_load path):
//   us3: [ds(4)][s3(165)][k(4)]      = 2640 floats
//   us2: [ds(4)][s2(45)][k(4 pad)]   =  720 floats (k=3 zero)
//   us1: [ds(4)][p(9)][k(2)]         =   72 floats
#define NS3 165
#define NS2 45
#define US3_FLOATS (NS3 * 16)       // 2640
#define US2_FLOATS (NS2 * 16)       //  720 (padded)
#define US1_FLOATS (9 * 8)          //   72

// Work split between the two halves (h = role>>2):
#define S3_SPLIT 83    // triples: h0 [0,83), h1 [83,165)
#define S2_SPLIT 23    // pairs:   h0 [0,23), h1 [23,45)
#define P1_SPLIT 5     // singles: h0 [0,5),  h1 [5,9)

typedef float pf2 __attribute__((ext_vector_type(2)));

// Compile-time index tables for the flattened symmetric triple loop.
struct Tab {
    unsigned char pairP[NS2], pairQ[NS2];
    unsigned char triPair[NS3], triI[NS3];
};
constexpr Tab makeTab() {
    Tab t{};
    int s2 = 0, s3 = 0;
    for (int p = 0; p < 9; p++)
        for (int q = p; q < 9; q++) {
            t.pairP[s2] = (unsigned char)p;
            t.pairQ[s2] = (unsigned char)q;
            for (int i = q; i < 9; i++) {
                t.triPair[s3] = (unsigned char)s2;
                t.triI[s3] = (unsigned char)i;
                s3++;
            }
            s2++;
        }
    return t;
}
constexpr Tab TAB = makeTab();

// Symmetrize u3/u2/u1 over index-permutation orbits (R12 layout).
__global__ __launch_bounds__(256) void build_sym_kernel(
    const float* __restrict__ u3_l0, const float* __restrict__ u2_l0, const float* __restrict__ u1_l0,
    const float* __restrict__ u3_l1, const float* __restrict__ u2_l1, const float* __restrict__ u1_l1,
    float* __restrict__ us3, float* __restrict__ us2, float* __restrict__ us1)
{
    int t = blockIdx.x * 256 + threadIdx.x;
    if (t < US3_FLOATS) {
        int k = t & 3;
        int rs = t >> 2;
        int s = rs % NS3;
        int ds = rs / NS3;
        int pp = 0, qq = 0, ii = 0, cntr = 0;
        for (int p = 0; p < 9; p++)
            for (int q = p; q < 9; q++)
                for (int i = q; i < 9; i++) {
                    if (cntr == s) { pp = p; qq = q; ii = i; }
                    cntr++;
                }
        const float* u = (ds == 0) ? u3_l0 : (u3_l1 + (ds - 1) * 2916);
        int perm[6][3] = {{pp,qq,ii},{pp,ii,qq},{qq,pp,ii},{qq,ii,pp},{ii,pp,qq},{ii,qq,pp}};
        float acc = 0.f;
        #pragma unroll
        for (int j = 0; j < 6; j++)
            acc += u[((perm[j][0] * 9 + perm[j][1]) * 9 + perm[j][2]) * 4 + k];
        float mult = (pp == qq && qq == ii) ? 6.f : ((pp == qq || qq == ii) ? 2.f : 1.f);
        us3[ds * (NS3 * 4) + s * 4 + k] = acc / mult;
    } else if (t < US3_FLOATS + US2_FLOATS) {
        int t2 = t - US3_FLOATS;
        int k = t2 & 3;
        int rs = t2 >> 2;
        int s = rs % NS2;
        int ds = rs / NS2;
        float v = 0.f;
        if (k < 3) {
            int pp = 0, qq = 0, cntr = 0;
            for (int p = 0; p < 9; p++)
                for (int q = p; q < 9; q++) {
                    if (cntr == s) { pp = p; qq = q; }
                    cntr++;
                }
            const float* u = (ds == 0) ? u2_l0 : (u2_l1 + (ds - 1) * 243);
            float acc = u[(pp * 9 + qq) * 3 + k] + u[(qq * 9 + pp) * 3 + k];
            v = (pp == qq) ? acc * 0.5f : acc;
        }
        us2[ds * (NS2 * 4) + s * 4 + k] = v;
    } else if (t < US3_FLOATS + US2_FLOATS + US1_FLOATS) {
        int t1 = t - US3_FLOATS - US2_FLOATS;
        int p = t1 >> 3, dk = t1 & 7, ds = dk >> 1, k = dk & 1;
        const float* u = (ds == 0) ? u1_l0 : (u1_l1 + (ds - 1) * 18);
        us1[ds * 18 + p * 2 + k] = u[p * 2 + k];
    }
}

// Fused contraction + o3.Linear + skip. One node per block.
// Block = 1024 = 128 c x 8 roles; role = (h = role>>2, ds = role&3).
// Each thread does HALF the triple/pair/single ranges for its dslot
// (~350 VALU, half of R12) -> 16 waves/block, 2 blocks/CU = 32 waves = 100%
// occupancy capacity (R12 sat at ~12 waves/CU; TLP, not ILP, is what has
// worked on this kernel: R7 win, R9/R13/R14 failures).
// Partials reduced via LDS (c-contiguous, conflict-free), then R12 epilogue.
__global__ __launch_bounds__(1024, 2) void fused_kernel(
    const float* __restrict__ x, const float* __restrict__ y,
    const float* __restrict__ us3, const float* __restrict__ us2, const float* __restrict__ us1,
    const float* __restrict__ w3_l0, const float* __restrict__ w2_l0, const float* __restrict__ w1_l0,
    const float* __restrict__ w3_l1, const float* __restrict__ w2_l1, const float* __restrict__ w1_l1,
    const float* __restrict__ lw0, const float* __restrict__ lw1,
    const float* __restrict__ sc, float* __restrict__ out)
{
    __shared__ float part[8 * 9 * 132];   // [role][k(9)][c] partials, 38016 B
    __shared__ float fs[4][132];          // [dslot][c]
    int tid = threadIdx.x;
    int c = tid & 127;
    int role = __builtin_amdgcn_readfirstlane(tid >> 7);  // wave-uniform (2 waves/role)
    int ds = role & 3;
    int h = role >> 2;
    int b = blockIdx.x;

    int e = 0;
    #pragma unroll
    for (int k = 1; k < E_EL; k++)
        if (y[b * E_EL + k] > 0.5f) e = k;
    e = __builtin_amdgcn_readfirstlane(e);

    float xv[9];
    {
        const float* xp = x + ((size_t)b * C_CH + c) * NIRR;
        #pragma unroll
        for (int i = 0; i < 9; i++) xv[i] = xp[i];
    }

    const float* t3 = us3 + ds * (NS3 * 4);
    const float* t2 = us2 + ds * (NS2 * 4);
    const float* t1 = us1 + ds * 18;
    const pf2* T3v = (const pf2*)t3;
    const pf2* T2v = (const pf2*)t2;
    const pf2* T1v = (const pf2*)t1;

    pf2 G3a = {0.f, 0.f}, G3b = {0.f, 0.f};
    pf2 G2a = {0.f, 0.f};
    float G2c = 0.f;
    pf2 G1v = {0.f, 0.f};

    if (h == 0) {
        #pragma unroll
        for (int p = 0; p < P1_SPLIT; p++) {
            pf2 xpv = {xv[p], xv[p]};
            G1v = __builtin_elementwise_fma(T1v[p], xpv, G1v);
        }
        #pragma unroll
        for (int s2 = 0; s2 < S2_SPLIT; s2++) {
            float pq2 = xv[TAB.pairP[s2]] * xv[TAB.pairQ[s2]];
            pf2 pqv = {pq2, pq2};
            G2a = __builtin_elementwise_fma(T2v[s2 * 2], pqv, G2a);
            G2c = __builtin_fmaf(t2[s2 * 4 + 2], pq2, G2c);
        }
        float pq = 0.f;
        #pragma unroll
        for (int s = 0; s < S3_SPLIT; s++) {
            const int pi = TAB.triPair[s];
            if (s == 0 || TAB.triPair[s] != TAB.triPair[s - 1])
                pq = xv[TAB.pairP[pi]] * xv[TAB.pairQ[pi]];
            float X = pq * xv[TAB.triI[s]];
            pf2 Xv = {X, X};
            G3a = __builtin_elementwise_fma(T3v[s * 2], Xv, G3a);
            G3b = __builtin_elementwise_fma(T3v[s * 2 + 1], Xv, G3b);
        }
    } else {
        #pragma unroll
        for (int p = P1_SPLIT; p < 9; p++) {
            pf2 xpv = {xv[p], xv[p]};
            G1v = __builtin_elementwise_fma(T1v[p], xpv, G1v);
        }
        #pragma unroll
        for (int s2 = S2_SPLIT; s2 < NS2; s2++) {
            float pq2 = xv[TAB.pairP[s2]] * xv[TAB.pairQ[s2]];
            pf2 pqv = {pq2, pq2};
            G2a = __builtin_elementwise_fma(T2v[s2 * 2], pqv, G2a);
            G2c = __builtin_fmaf(t2[s2 * 4 + 2], pq2, G2c);
        }
        float pq = 0.f;
        #pragma unroll
        for (int s = S3_SPLIT; s < NS3; s++) {
            const int pi = TAB.triPair[s];
            if (s == S3_SPLIT || TAB.triPair[s] != TAB.triPair[s - 1])
                pq = xv[TAB.pairP[pi]] * xv[TAB.pairQ[pi]];
            float X = pq * xv[TAB.triI[s]];
            pf2 Xv = {X, X};
            G3a = __builtin_elementwise_fma(T3v[s * 2], Xv, G3a);
            G3b = __builtin_elementwise_fma(T3v[s * 2 + 1], Xv, G3b);
        }
    }

    // write partials: part[role][k][c]
    {
        float G[9] = {G3a.x, G3a.y, G3b.x, G3b.y, G2a.x, G2a.y, G2c, G1v.x, G1v.y};
        #pragma unroll
        for (int k = 0; k < 9; k++)
            part[(role * 9 + k) * 132 + c] = G[k];
    }
    __syncthreads();

    // roles 0..3: reduce halves + weight-contract
    if (tid < 512) {
        float G[9];
        #pragma unroll
        for (int k = 0; k < 9; k++)
            G[k] = part[(role * 9 + k) * 132 + c] + part[((role + 4) * 9 + k) * 132 + c];

        // element weights (lane c): w3 (E,4,C), w2 (E,3,C), w1 (E,2,C)
        float acc = 0.f;
        if (role == 0) {
            #pragma unroll
            for (int k = 0; k < 4; k++) acc += w3_l0[(e * 4 + k) * 128 + c] * G[k];
            #pragma unroll
            for (int k = 0; k < 3; k++) acc += w2_l0[(e * 3 + k) * 128 + c] * G[4 + k];
            #pragma unroll
            for (int k = 0; k < 2; k++) acc += w1_l0[(e * 2 + k) * 128 + c] * G[7 + k];
        } else {
            #pragma unroll
            for (int k = 0; k < 4; k++) acc += w3_l1[(e * 4 + k) * 128 + c] * G[k];
            #pragma unroll
            for (int k = 0; k < 3; k++) acc += w2_l1[(e * 3 + k) * 128 + c] * G[4 + k];
            #pragma unroll
            for (int k = 0; k < 2; k++) acc += w1_l1[(e * 2 + k) * 128 + c] * G[7 + k];
        }
        fs[role][c] = acc;
    }
    __syncthreads();

    // ---- o3.Linear + skip: threads 0..127 only, 4 contiguous j-cols each ----
    if (tid < 128) {
        int sel, m = 0, j0;
        const float4* W4;
        bool isl0 = (tid < 32);
        if (isl0) { sel = 0; j0 = 4 * tid; W4 = (const float4*)lw0; }
        else {
            int idx = tid - 32;
            m = idx >> 5;
            j0 = 4 * (idx & 31);
            sel = 1 + m;
            W4 = (const float4*)lw1;
        }
        int wbase = j0 >> 2;

        float a0 = 0.f, a1 = 0.f, a2 = 0.f, a3 = 0.f;
        #pragma unroll 4
        for (int ib = 0; ib < 32; ib++) {
            float4 f = *(const float4*)&fs[sel][4 * ib];
            float4 w0 = W4[(4 * ib + 0) * 32 + wbase];
            float4 w1 = W4[(4 * ib + 1) * 32 + wbase];
            float4 w2 = W4[(4 * ib + 2) * 32 + wbase];
            float4 w3 = W4[(4 * ib + 3) * 32 + wbase];
            a0 += f.x * w0.x + f.y * w1.x + f.z * w2.x + f.w * w3.x;
            a1 += f.x * w0.y + f.y * w1.y + f.z * w2.y + f.w * w3.y;
            a2 += f.x * w0.z + f.y * w1.z + f.z * w2.z + f.w * w3.z;
            a3 += f.x * w0.w + f.y * w1.w + f.z * w2.w + f.w * w3.w;
        }

        const float inv_sqrt_c = 0.08838834764831845f;  // 1/sqrt(128)
        if (isl0) {
            size_t o = (size_t)b * 512 + j0;
            float4 s = *(const float4*)(sc + o);
            float4 rr;
            rr.x = a0 * inv_sqrt_c + s.x;
            rr.y = a1 * inv_sqrt_c + s.y;
            rr.z = a2 * inv_sqrt_c + s.z;
            rr.w = a3 * inv_sqrt_c + s.w;
            *(float4*)(out + o) = rr;
        } else {
            float av[4] = {a0, a1, a2, a3};
            #pragma unroll
            for (int jj = 0; jj < 4; jj++) {
                size_t o = (size_t)b * 512 + 128 + 3 * (j0 + jj) + m;
                out[o] = av[jj] * inv_sqrt_c + sc[o];
            }
        }
    }
}

extern "C" void kernel_launch(void* const* d_in, const int* in_sizes, int n_in,
                              void* d_out, int out_size, void* d_ws, size_t ws_size,
                              hipStream_t stream) {
    const float* x     = (const float*)d_in[0];
    const float* y     = (const float*)d_in[1];
    const float* sc    = (const float*)d_in[2];
    const float* u3_l0 = (const float*)d_in[3];
    const float* u2_l0 = (const float*)d_in[4];
    const float* u1_l0 = (const float*)d_in[5];
    const float* w3_l0 = (const float*)d_in[6];
    const float* w2_l0 = (const float*)d_in[7];
    const float* w1_l0 = (const float*)d_in[8];
    const float* u3_l1 = (const float*)d_in[9];
    const float* u2_l1 = (const float*)d_in[10];
    const float* u1_l1 = (const float*)d_in[11];
    const float* w3_l1 = (const float*)d_in[12];
    const float* w2_l1 = (const float*)d_in[13];
    const float* w1_l1 = (const float*)d_in[14];
    const float* lw0   = (const float*)d_in[15];
    const float* lw1   = (const float*)d_in[16];
    float* out = (float*)d_out;

    // Workspace layout (floats): us3 | us2 | us1
    float* us3 = (float*)d_ws;
    float* us2 = us3 + US3_FLOATS;
    float* us1 = us2 + US2_FLOATS;

    int tot = US3_FLOATS + US2_FLOATS + US1_FLOATS;
    build_sym_kernel<<<(tot + 255) / 256, 256, 0, stream>>>(
        u3_l0, u2_l0, u1_l0, u3_l1, u2_l1, u1_l1, us3, us2, us1);
    fused_kernel<<<N_NODES, 1024, 0, stream>>>(
        x, y, us3, us2, us1,
        w3_l0, w2_l0, w1_l0, w3_l1, w2_l1, w1_l1,
        lw0, lw1, sc, out);
}

// Round 17
// 120.708 us; speedup vs baseline: 1.1915x; 1.1593x over previous
//
#include <hip/hip_runtime.h>

// Problem constants (from reference)
#define N_NODES 2048
#define C_CH    128
#define NIRR    9
#define E_EL    10
// dslot mapping: 0 -> l0 (d=0), 1..3 -> l1 (d=0..2)
//
// MFMA formulation: G[36] per (node,c) column = U_sym[36x219] . M[219] where
// M = monomials {x_p x_q x_i (165, p<=q<=i), x_p x_q (45), x_p (9)} + 5 pad.
// Row map (32 MFMA rows): 0-15 G3(ds*4+k), 16-27 G2(ds*3+k), 28-31 G1(ds<2).
// G1 rows for ds=2,3 (4 values) are done in VALU in the epilogue.
// K = 224 = 14 tiles of 16. Shape: mfma_f32_32x32x16_f16 (C/D layout
// verified m74/m101: col=lane&31, row=(reg&3)+8*(reg>>2)+4*(lane>>5);
// A: m=lane&31, k=(lane>>5)*8+j; B mirrored).

#define NKT 14
#define UTAB_HALVES (NKT * 512)    // 7168

typedef _Float16 f16x8 __attribute__((ext_vector_type(8)));
typedef float   f32x16 __attribute__((ext_vector_type(16)));

// Monomial index tables: M[k] = msk[k] * xv10[a]*xv10[b2]*xv10[c], xv10[9]=1.
struct MonoTab {
    unsigned char a[224], b2[224], c[224], msk[224];
};
constexpr MonoTab makeMono() {
    MonoTab m{};
    int s3 = 0;
    for (int p = 0; p < 9; p++)
        for (int q = p; q < 9; q++)
            for (int i = q; i < 9; i++) { m.a[s3] = p; m.b2[s3] = q; m.c[s3] = i; m.msk[s3] = 1; s3++; }
    int s2 = 0;
    for (int p = 0; p < 9; p++)
        for (int q = p; q < 9; q++) { m.a[165 + s2] = p; m.b2[165 + s2] = q; m.c[165 + s2] = 9; m.msk[165 + s2] = 1; s2++; }
    for (int p = 0; p < 9; p++) { m.a[210 + p] = p; m.b2[210 + p] = 9; m.c[210 + p] = 9; m.msk[210 + p] = 1; }
    for (int k = 219; k < 224; k++) { m.a[k] = 9; m.b2[k] = 9; m.c[k] = 9; m.msk[k] = 0; }
    return m;
}
constexpr MonoTab MT = makeMono();

// Build U_sym directly into the A-fragment layout (f16) + fp32 us1f table.
__global__ __launch_bounds__(256) void build_utab_kernel(
    const float* __restrict__ u3_l0, const float* __restrict__ u2_l0, const float* __restrict__ u1_l0,
    const float* __restrict__ u3_l1, const float* __restrict__ u2_l1, const float* __restrict__ u1_l1,
    _Float16* __restrict__ Utab, float* __restrict__ us1f)
{
    int t = blockIdx.x * 256 + threadIdx.x;
    if (t < UTAB_HALVES) {
        int kt = t / 512, idx = t % 512;
        int lane = idx >> 3, j = idx & 7;
        int m = lane & 31, g = lane >> 5;
        int k = kt * 16 + g * 8 + j;
        float v = 0.f;
        if (m < 16) {                       // G3 rows: ds*4+kk, k in [0,165)
            int ds = m >> 2, kk = m & 3;
            if (k < 165) {
                int pp = 0, qq = 0, ii = 0, cnt = 0;
                for (int p = 0; p < 9; p++)
                    for (int q = p; q < 9; q++)
                        for (int i = q; i < 9; i++) {
                            if (cnt == k) { pp = p; qq = q; ii = i; }
                            cnt++;
                        }
                const float* u = (ds == 0) ? u3_l0 : (u3_l1 + (ds - 1) * 2916);
                int perm[6][3] = {{pp,qq,ii},{pp,ii,qq},{qq,pp,ii},{qq,ii,pp},{ii,pp,qq},{ii,qq,pp}};
                float acc = 0.f;
                #pragma unroll
                for (int w = 0; w < 6; w++)
                    acc += u[((perm[w][0] * 9 + perm[w][1]) * 9 + perm[w][2]) * 4 + kk];
                float mult = (pp == qq && qq == ii) ? 6.f : ((pp == qq || qq == ii) ? 2.f : 1.f);
                v = acc / mult;
            }
        } else if (m < 28) {                // G2 rows: ds*3+kk, k in [165,210)
            int r = m - 16, ds = r / 3, kk = r % 3;
            if (k >= 165 && k < 210) {
                int s = k - 165;
                int pp = 0, qq = 0, cnt = 0;
                for (int p = 0; p < 9; p++)
                    for (int q = p; q < 9; q++) {
                        if (cnt == s) { pp = p; qq = q; }
                        cnt++;
                    }
                const float* u = (ds == 0) ? u2_l0 : (u2_l1 + (ds - 1) * 243);
                float acc = u[(pp * 9 + qq) * 3 + kk] + u[(qq * 9 + pp) * 3 + kk];
                v = (pp == qq) ? acc * 0.5f : acc;
            }
        } else {                            // G1 rows ds in {0,1}: k in [210,219)
            int r = m - 28, ds = r >> 1, kk = r & 1;
            if (k >= 210 && k < 219) {
                int p = k - 210;
                v = (ds == 0) ? u1_l0[p * 2 + kk] : u1_l1[(0 * 9 + p) * 2 + kk];
            }
        }
        Utab[t] = (_Float16)v;
    } else if (t < UTAB_HALVES + 72) {
        int q = t - UTAB_HALVES;
        int ds = q / 18, rem = q % 18, p = rem >> 1, kk = rem & 1;
        us1f[q] = (ds == 0) ? u1_l0[p * 2 + kk] : u1_l1[((ds - 1) * 9 + p) * 2 + kk];
    }
}

// Fused MFMA contraction + o3.Linear + skip. Block = 256 threads (4 waves),
// 2 nodes (256 columns). Each wave does 2 column-tiles of 32; per tile the
// K-loop is 14 x { A-frag load (coalesced dwordx4, L1-hot), 8 monomials
// (compile-time indices, 2-way g-divergence), 1 MFMA }. Accumulator staged
// to LDS Gbuf, then per-column w-contract + linear epilogue (R12 form).
__global__ __launch_bounds__(256, 2) void fused_kernel(
    const float* __restrict__ x, const float* __restrict__ y,
    const _Float16* __restrict__ Utab, const float* __restrict__ us1f,
    const float* __restrict__ w3_l0, const float* __restrict__ w2_l0, const float* __restrict__ w1_l0,
    const float* __restrict__ w3_l1, const float* __restrict__ w2_l1, const float* __restrict__ w1_l1,
    const float* __restrict__ lw0, const float* __restrict__ lw1,
    const float* __restrict__ sc, float* __restrict__ out)
{
    __shared__ float Gbuf[256][34];   // [col][row 0..31], pad 34: b64-aligned, 2-way max
    __shared__ float fs[2][4][132];   // [node][dslot][c]
    int tid = threadIdx.x;
    int lane = tid & 63;
    int wid = tid >> 6;
    int n = lane & 31, g = lane >> 5;
    int b0 = blockIdx.x * 2;

    const f16x8* U8 = (const f16x8*)Utab;

    #pragma unroll 1
    for (int tl = 0; tl < 2; tl++) {
        int tile = wid * 2 + tl;
        int col = tile * 32 + n;
        int node = col >> 7, c = col & 127;
        const float* xp = x + ((size_t)(b0 + node) * C_CH + c) * NIRR;
        float xv10[10];
        #pragma unroll
        for (int i = 0; i < 9; i++) xv10[i] = xp[i];
        xv10[9] = 1.f;

        f32x16 acc;
        #pragma unroll
        for (int z = 0; z < 16; z++) acc[z] = 0.f;

        #pragma unroll
        for (int kt = 0; kt < NKT; kt++) {
            f16x8 af = U8[kt * 64 + lane];
            float mf[8];
            if (g == 0) {
                #pragma unroll
                for (int j = 0; j < 8; j++) {
                    const int k = kt * 16 + j;
                    mf[j] = MT.msk[k] ? xv10[MT.a[k]] * xv10[MT.b2[k]] * xv10[MT.c[k]] : 0.f;
                }
            } else {
                #pragma unroll
                for (int j = 0; j < 8; j++) {
                    const int k = kt * 16 + 8 + j;
                    mf[j] = MT.msk[k] ? xv10[MT.a[k]] * xv10[MT.b2[k]] * xv10[MT.c[k]] : 0.f;
                }
            }
            f16x8 bf;
            #pragma unroll
            for (int j = 0; j < 8; j++) bf[j] = (_Float16)mf[j];
            acc = __builtin_amdgcn_mfma_f32_32x32x16_f16(af, bf, acc, 0, 0, 0);
        }

        // stage C/D -> Gbuf: row = (reg&3) + 8*(reg>>2) + 4*g  [m74/m101]
        #pragma unroll
        for (int reg = 0; reg < 16; reg++) {
            int row = (reg & 3) + 8 * (reg >> 2) + 4 * g;
            Gbuf[col][row] = acc[reg];
        }
    }
    __syncthreads();

    // ---- per-column w-contract: thread tid <-> column tid ----
    {
        int col = tid;
        int node = col >> 7, c = col & 127;
        int b = b0 + node;
        int e = 0;
        #pragma unroll
        for (int k = 1; k < E_EL; k++)
            if (y[b * E_EL + k] > 0.5f) e = k;
        e = __builtin_amdgcn_readfirstlane(e);   // node uniform per wave

        float G[32];
        #pragma unroll
        for (int row = 0; row < 32; row++) G[row] = Gbuf[col][row];

        float xvp[9];
        {
            const float* xp = x + ((size_t)b * C_CH + c) * NIRR;
            #pragma unroll
            for (int i = 0; i < 9; i++) xvp[i] = xp[i];
        }
        // G1 rows for ds=2,3 via VALU (9-term dots, wave-uniform us1f)
        float G1hi[4];
        #pragma unroll
        for (int dd = 0; dd < 2; dd++) {
            #pragma unroll
            for (int kk = 0; kk < 2; kk++) {
                float a = 0.f;
                #pragma unroll
                for (int p = 0; p < 9; p++)
                    a += us1f[(2 + dd) * 18 + p * 2 + kk] * xvp[p];
                G1hi[dd * 2 + kk] = a;
            }
        }

        // f[0] with l0 weights
        {
            float acc0 = 0.f;
            #pragma unroll
            for (int kk = 0; kk < 4; kk++) acc0 += w3_l0[(e * 4 + kk) * 128 + c] * G[kk];
            #pragma unroll
            for (int kk = 0; kk < 3; kk++) acc0 += w2_l0[(e * 3 + kk) * 128 + c] * G[16 + kk];
            #pragma unroll
            for (int kk = 0; kk < 2; kk++) acc0 += w1_l0[(e * 2 + kk) * 128 + c] * G[28 + kk];
            fs[node][0][c] = acc0;
        }
        // f[1..3] with l1 weights
        #pragma unroll
        for (int ds = 1; ds < 4; ds++) {
            float a = 0.f;
            #pragma unroll
            for (int kk = 0; kk < 4; kk++) a += w3_l1[(e * 4 + kk) * 128 + c] * G[ds * 4 + kk];
            #pragma unroll
            for (int kk = 0; kk < 3; kk++) a += w2_l1[(e * 3 + kk) * 128 + c] * G[16 + ds * 3 + kk];
            #pragma unroll
            for (int kk = 0; kk < 2; kk++) {
                float g1 = (ds < 2) ? G[28 + ds * 2 + kk] : G1hi[(ds - 2) * 2 + kk];
                a += w1_l1[(e * 2 + kk) * 128 + c] * g1;
            }
            fs[node][ds][c] = a;
        }
    }
    __syncthreads();

    // ---- o3.Linear + skip: threads 0..255, thread (nn, t) owns 4 j-cols ----
    {
        int nn = tid >> 7;
        int t = tid & 127;
        int b = b0 + nn;
        int sel, m = 0, j0;
        const float4* W4;
        bool isl0 = (t < 32);
        if (isl0) { sel = 0; j0 = 4 * t; W4 = (const float4*)lw0; }
        else {
            int idx = t - 32;
            m = idx >> 5;
            j0 = 4 * (idx & 31);
            sel = 1 + m;
            W4 = (const float4*)lw1;
        }
        int wbase = j0 >> 2;

        float a0 = 0.f, a1 = 0.f, a2 = 0.f, a3 = 0.f;
        #pragma unroll 4
        for (int ib = 0; ib < 32; ib++) {
            float4 f = *(const float4*)&fs[nn][sel][4 * ib];
            float4 w0 = W4[(4 * ib + 0) * 32 + wbase];
            float4 w1 = W4[(4 * ib + 1) * 32 + wbase];
            float4 w2 = W4[(4 * ib + 2) * 32 + wbase];
            float4 w3 = W4[(4 * ib + 3) * 32 + wbase];
            a0 += f.x * w0.x + f.y * w1.x + f.z * w2.x + f.w * w3.x;
            a1 += f.x * w0.y + f.y * w1.y + f.z * w2.y + f.w * w3.y;
            a2 += f.x * w0.z + f.y * w1.z + f.z * w2.z + f.w * w3.z;
            a3 += f.x * w0.w + f.y * w1.w + f.z * w2.w + f.w * w3.w;
        }

        const float inv_sqrt_c = 0.08838834764831845f;  // 1/sqrt(128)
        if (isl0) {
            size_t o = (size_t)b * 512 + j0;
            float4 s = *(const float4*)(sc + o);
            float4 rr;
            rr.x = a0 * inv_sqrt_c + s.x;
            rr.y = a1 * inv_sqrt_c + s.y;
            rr.z = a2 * inv_sqrt_c + s.z;
            rr.w = a3 * inv_sqrt_c + s.w;
            *(float4*)(out + o) = rr;
        } else {
            float av[4] = {a0, a1, a2, a3};
            #pragma unroll
            for (int jj = 0; jj < 4; jj++) {
                size_t o = (size_t)b * 512 + 128 + 3 * (j0 + jj) + m;
                out[o] = av[jj] * inv_sqrt_c + sc[o];
            }
        }
    }
}

extern "C" void kernel_launch(void* const* d_in, const int* in_sizes, int n_in,
                              void* d_out, int out_size, void* d_ws, size_t ws_size,
                              hipStream_t stream) {
    const float* x     = (const float*)d_in[0];
    const float* y     = (const float*)d_in[1];
    const float* sc    = (const float*)d_in[2];
    const float* u3_l0 = (const float*)d_in[3];
    const float* u2_l0 = (const float*)d_in[4];
    const float* u1_l0 = (const float*)d_in[5];
    const float* w3_l0 = (const float*)d_in[6];
    const float* w2_l0 = (const float*)d_in[7];
    const float* w1_l0 = (const float*)d_in[8];
    const float* u3_l1 = (const float*)d_in[9];
    const float* u2_l1 = (const float*)d_in[10];
    const float* u1_l1 = (const float*)d_in[11];
    const float* w3_l1 = (const float*)d_in[12];
    const float* w2_l1 = (const float*)d_in[13];
    const float* w1_l1 = (const float*)d_in[14];
    const float* lw0   = (const float*)d_in[15];
    const float* lw1   = (const float*)d_in[16];
    float* out = (float*)d_out;

    // Workspace: Utab (f16, 14336 B) | us1f (fp32, 288 B)
    _Float16* Utab = (_Float16*)d_ws;
    float* us1f = (float*)((char*)d_ws + UTAB_HALVES * 2);

    build_utab_kernel<<<(UTAB_HALVES + 72 + 255) / 256, 256, 0, stream>>>(
        u3_l0, u2_l0, u1_l0, u3_l1, u2_l1, u1_l1, Utab, us1f);
    fused_kernel<<<N_NODES / 2, 256, 0, stream>>>(
        x, y, Utab, us1f,
        w3_l0, w2_l0, w1_l0, w3_l1, w2_l1, w1_l1,
        lw0, lw1, sc, out);
}

// Round 18
// 120.501 us; speedup vs baseline: 1.1935x; 1.0017x over previous
//
#include <hip/hip_runtime.h>

// Problem constants (from reference)
#define N_NODES 2048
#define C_CH    128
#define NIRR    9
#define E_EL    10
// dslot mapping: 0 -> l0 (d=0), 1..3 -> l1 (d=0..2)
//
// MFMA formulation: G[36] per (node,c) column = U_sym[36x219] . M[219] where
// M = monomials {x_p x_q x_i (165, p<=q<=i), x_p x_q (45), x_p (9)} + 5 pad.
// Row map (32 MFMA rows): 0-15 G3(ds*4+k), 16-27 G2(ds*3+k), 28-31 G1(ds<2).
// G1 rows for ds=2,3 (4 values) are done in VALU in the epilogue.
// K = 224 = 14 tiles of 16. Shape: mfma_f32_32x32x16_f16 (C/D layout
// verified m74/m101: col=lane&31, row=(reg&3)+8*(reg>>2)+4*(lane>>5);
// A: m=lane&31, k=(lane>>5)*8+j; B mirrored).

#define NKT 14
#define UTAB_HALVES (NKT * 512)    // 7168

typedef _Float16 f16x8 __attribute__((ext_vector_type(8)));
typedef float   f32x16 __attribute__((ext_vector_type(16)));
typedef float   f32x4u __attribute__((ext_vector_type(4), aligned(4)));
typedef float   pf2    __attribute__((ext_vector_type(2)));

// Monomial index tables: M[k] = msk[k] * xv10[a]*xv10[b2]*xv10[c], xv10[9]=1.
struct MonoTab {
    unsigned char a[224], b2[224], c[224], msk[224];
};
constexpr MonoTab makeMono() {
    MonoTab m{};
    int s3 = 0;
    for (int p = 0; p < 9; p++)
        for (int q = p; q < 9; q++)
            for (int i = q; i < 9; i++) { m.a[s3] = p; m.b2[s3] = q; m.c[s3] = i; m.msk[s3] = 1; s3++; }
    int s2 = 0;
    for (int p = 0; p < 9; p++)
        for (int q = p; q < 9; q++) { m.a[165 + s2] = p; m.b2[165 + s2] = q; m.c[165 + s2] = 9; m.msk[165 + s2] = 1; s2++; }
    for (int p = 0; p < 9; p++) { m.a[210 + p] = p; m.b2[210 + p] = 9; m.c[210 + p] = 9; m.msk[210 + p] = 1; }
    for (int k = 219; k < 224; k++) { m.a[k] = 9; m.b2[k] = 9; m.c[k] = 9; m.msk[k] = 0; }
    return m;
}
constexpr MonoTab MT = makeMono();

// Build U_sym directly into the A-fragment layout (f16) + fp32 us1f table.
__global__ __launch_bounds__(256) void build_utab_kernel(
    const float* __restrict__ u3_l0, const float* __restrict__ u2_l0, const float* __restrict__ u1_l0,
    const float* __restrict__ u3_l1, const float* __restrict__ u2_l1, const float* __restrict__ u1_l1,
    _Float16* __restrict__ Utab, float* __restrict__ us1f)
{
    int t = blockIdx.x * 256 + threadIdx.x;
    if (t < UTAB_HALVES) {
        int kt = t / 512, idx = t % 512;
        int lane = idx >> 3, j = idx & 7;
        int m = lane & 31, g = lane >> 5;
        int k = kt * 16 + g * 8 + j;
        float v = 0.f;
        if (m < 16) {                       // G3 rows: ds*4+kk, k in [0,165)
            int ds = m >> 2, kk = m & 3;
            if (k < 165) {
                int pp = 0, qq = 0, ii = 0, cnt = 0;
                for (int p = 0; p < 9; p++)
                    for (int q = p; q < 9; q++)
                        for (int i = q; i < 9; i++) {
                            if (cnt == k) { pp = p; qq = q; ii = i; }
                            cnt++;
                        }
                const float* u = (ds == 0) ? u3_l0 : (u3_l1 + (ds - 1) * 2916);
                int perm[6][3] = {{pp,qq,ii},{pp,ii,qq},{qq,pp,ii},{qq,ii,pp},{ii,pp,qq},{ii,qq,pp}};
                float acc = 0.f;
                #pragma unroll
                for (int w = 0; w < 6; w++)
                    acc += u[((perm[w][0] * 9 + perm[w][1]) * 9 + perm[w][2]) * 4 + kk];
                float mult = (pp == qq && qq == ii) ? 6.f : ((pp == qq || qq == ii) ? 2.f : 1.f);
                v = acc / mult;
            }
        } else if (m < 28) {                // G2 rows: ds*3+kk, k in [165,210)
            int r = m - 16, ds = r / 3, kk = r % 3;
            if (k >= 165 && k < 210) {
                int s = k - 165;
                int pp = 0, qq = 0, cnt = 0;
                for (int p = 0; p < 9; p++)
                    for (int q = p; q < 9; q++) {
                        if (cnt == s) { pp = p; qq = q; }
                        cnt++;
                    }
                const float* u = (ds == 0) ? u2_l0 : (u2_l1 + (ds - 1) * 243);
                float acc = u[(pp * 9 + qq) * 3 + kk] + u[(qq * 9 + pp) * 3 + kk];
                v = (pp == qq) ? acc * 0.5f : acc;
            }
        } else {                            // G1 rows ds in {0,1}: k in [210,219)
            int r = m - 28, ds = r >> 1, kk = r & 1;
            if (k >= 210 && k < 219) {
                int p = k - 210;
                v = (ds == 0) ? u1_l0[p * 2 + kk] : u1_l1[(0 * 9 + p) * 2 + kk];
            }
        }
        Utab[t] = (_Float16)v;
    } else if (t < UTAB_HALVES + 72) {
        int q = t - UTAB_HALVES;
        int ds = q / 18, rem = q % 18, p = rem >> 1, kk = rem & 1;
        us1f[q] = (ds == 0) ? u1_l0[p * 2 + kk] : u1_l1[((ds - 1) * 9 + p) * 2 + kk];
    }
}

// Fused MFMA contraction + o3.Linear + skip. Block = 256 threads (4 waves),
// 2 nodes (256 columns). x loads use aligned(4) float4 (3 gather insts vs 9);
// linear epilogue uses v_pk_fma_f32 (256 pk vs 512 scalar FMA).
__global__ __launch_bounds__(256, 2) void fused_kernel(
    const float* __restrict__ x, const float* __restrict__ y,
    const _Float16* __restrict__ Utab, const float* __restrict__ us1f,
    const float* __restrict__ w3_l0, const float* __restrict__ w2_l0, const float* __restrict__ w1_l0,
    const float* __restrict__ w3_l1, const float* __restrict__ w2_l1, const float* __restrict__ w1_l1,
    const float* __restrict__ lw0, const float* __restrict__ lw1,
    const float* __restrict__ sc, float* __restrict__ out)
{
    __shared__ float Gbuf[256][34];   // [col][row 0..31]
    __shared__ float fs[2][4][132];   // [node][dslot][c]
    int tid = threadIdx.x;
    int lane = tid & 63;
    int wid = tid >> 6;
    int n = lane & 31, g = lane >> 5;
    int b0 = blockIdx.x * 2;

    const f16x8* U8 = (const f16x8*)Utab;

    #pragma unroll 1
    for (int tl = 0; tl < 2; tl++) {
        int tile = wid * 2 + tl;
        int col = tile * 32 + n;
        int node = col >> 7, c = col & 127;
        const float* xp = x + ((size_t)(b0 + node) * C_CH + c) * NIRR;
        f32x4u xa = *(const f32x4u*)xp;
        f32x4u xb = *(const f32x4u*)(xp + 4);
        float xv10[10] = {xa[0], xa[1], xa[2], xa[3], xb[0], xb[1], xb[2], xb[3], xp[8], 1.f};

        f32x16 acc;
        #pragma unroll
        for (int z = 0; z < 16; z++) acc[z] = 0.f;

        #pragma unroll
        for (int kt = 0; kt < NKT; kt++) {
            f16x8 af = U8[kt * 64 + lane];
            float mf[8];
            if (g == 0) {
                #pragma unroll
                for (int j = 0; j < 8; j++) {
                    const int k = kt * 16 + j;
                    mf[j] = MT.msk[k] ? xv10[MT.a[k]] * xv10[MT.b2[k]] * xv10[MT.c[k]] : 0.f;
                }
            } else {
                #pragma unroll
                for (int j = 0; j < 8; j++) {
                    const int k = kt * 16 + 8 + j;
                    mf[j] = MT.msk[k] ? xv10[MT.a[k]] * xv10[MT.b2[k]] * xv10[MT.c[k]] : 0.f;
                }
            }
            f16x8 bf;
            #pragma unroll
            for (int j = 0; j < 8; j++) bf[j] = (_Float16)mf[j];
            acc = __builtin_amdgcn_mfma_f32_32x32x16_f16(af, bf, acc, 0, 0, 0);
        }

        // stage C/D -> Gbuf: row = (reg&3) + 8*(reg>>2) + 4*g  [m74/m101]
        #pragma unroll
        for (int reg = 0; reg < 16; reg++) {
            int row = (reg & 3) + 8 * (reg >> 2) + 4 * g;
            Gbuf[col][row] = acc[reg];
        }
    }
    __syncthreads();

    // ---- per-column w-contract: thread tid <-> column tid ----
    {
        int col = tid;
        int node = col >> 7, c = col & 127;
        int b = b0 + node;
        int e = 0;
        #pragma unroll
        for (int k = 1; k < E_EL; k++)
            if (y[b * E_EL + k] > 0.5f) e = k;
        e = __builtin_amdgcn_readfirstlane(e);   // node uniform per wave

        float G[32];
        #pragma unroll
        for (int row = 0; row < 32; row++) G[row] = Gbuf[col][row];

        const float* xp = x + ((size_t)b * C_CH + c) * NIRR;
        f32x4u xa = *(const f32x4u*)xp;
        f32x4u xb = *(const f32x4u*)(xp + 4);
        float xvp[9] = {xa[0], xa[1], xa[2], xa[3], xb[0], xb[1], xb[2], xb[3], xp[8]};

        // G1 rows for ds=2,3 via VALU (9-term dots, wave-uniform us1f)
        float G1hi[4];
        #pragma unroll
        for (int dd = 0; dd < 2; dd++) {
            #pragma unroll
            for (int kk = 0; kk < 2; kk++) {
                float a = 0.f;
                #pragma unroll
                for (int p = 0; p < 9; p++)
                    a += us1f[(2 + dd) * 18 + p * 2 + kk] * xvp[p];
                G1hi[dd * 2 + kk] = a;
            }
        }

        // f[0] with l0 weights
        {
            float acc0 = 0.f;
            #pragma unroll
            for (int kk = 0; kk < 4; kk++) acc0 += w3_l0[(e * 4 + kk) * 128 + c] * G[kk];
            #pragma unroll
            for (int kk = 0; kk < 3; kk++) acc0 += w2_l0[(e * 3 + kk) * 128 + c] * G[16 + kk];
            #pragma unroll
            for (int kk = 0; kk < 2; kk++) acc0 += w1_l0[(e * 2 + kk) * 128 + c] * G[28 + kk];
            fs[node][0][c] = acc0;
        }
        // f[1..3] with l1 weights
        #pragma unroll
        for (int ds = 1; ds < 4; ds++) {
            float a = 0.f;
            #pragma unroll
            for (int kk = 0; kk < 4; kk++) a += w3_l1[(e * 4 + kk) * 128 + c] * G[ds * 4 + kk];
            #pragma unroll
            for (int kk = 0; kk < 3; kk++) a += w2_l1[(e * 3 + kk) * 128 + c] * G[16 + ds * 3 + kk];
            #pragma unroll
            for (int kk = 0; kk < 2; kk++) {
                float g1 = (ds < 2) ? G[28 + ds * 2 + kk] : G1hi[(ds - 2) * 2 + kk];
                a += w1_l1[(e * 2 + kk) * 128 + c] * g1;
            }
            fs[node][ds][c] = a;
        }
    }
    __syncthreads();

    // ---- o3.Linear + skip: threads 0..255, thread (nn, t) owns 4 j-cols ----
    {
        int nn = tid >> 7;
        int t = tid & 127;
        int b = b0 + nn;
        int sel, m = 0, j0;
        const float4* W4;
        bool isl0 = (t < 32);
        if (isl0) { sel = 0; j0 = 4 * t; W4 = (const float4*)lw0; }
        else {
            int idx = t - 32;
            m = idx >> 5;
            j0 = 4 * (idx & 31);
            sel = 1 + m;
            W4 = (const float4*)lw1;
        }
        int wbase = j0 >> 2;

        pf2 ap01 = {0.f, 0.f}, ap23 = {0.f, 0.f};
        #pragma unroll 4
        for (int ib = 0; ib < 32; ib++) {
            float4 f = *(const float4*)&fs[nn][sel][4 * ib];
            float fr[4] = {f.x, f.y, f.z, f.w};
            #pragma unroll
            for (int r = 0; r < 4; r++) {
                float4 w = W4[(4 * ib + r) * 32 + wbase];
                pf2 wlo = {w.x, w.y};
                pf2 whi = {w.z, w.w};
                pf2 fsp = {fr[r], fr[r]};
                ap01 = __builtin_elementwise_fma(wlo, fsp, ap01);
                ap23 = __builtin_elementwise_fma(whi, fsp, ap23);
            }
        }
        float a0 = ap01[0], a1 = ap01[1], a2 = ap23[0], a3 = ap23[1];

        const float inv_sqrt_c = 0.08838834764831845f;  // 1/sqrt(128)
        if (isl0) {
            size_t o = (size_t)b * 512 + j0;
            float4 s = *(const float4*)(sc + o);
            float4 rr;
            rr.x = a0 * inv_sqrt_c + s.x;
            rr.y = a1 * inv_sqrt_c + s.y;
            rr.z = a2 * inv_sqrt_c + s.z;
            rr.w = a3 * inv_sqrt_c + s.w;
            *(float4*)(out + o) = rr;
        } else {
            float av[4] = {a0, a1, a2, a3};
            #pragma unroll
            for (int jj = 0; jj < 4; jj++) {
                size_t o = (size_t)b * 512 + 128 + 3 * (j0 + jj) + m;
                out[o] = av[jj] * inv_sqrt_c + sc[o];
            }
        }
    }
}

extern "C" void kernel_launch(void* const* d_in, const int* in_sizes, int n_in,
                              void* d_out, int out_size, void* d_ws, size_t ws_size,
                              hipStream_t stream) {
    const float* x     = (const float*)d_in[0];
    const float* y     = (const float*)d_in[1];
    const float* sc    = (const float*)d_in[2];
    const float* u3_l0 = (const float*)d_in[3];
    const float* u2_l0 = (const float*)d_in[4];
    const float* u1_l0 = (const float*)d_in[5];
    const float* w3_l0 = (const float*)d_in[6];
    const float* w2_l0 = (const float*)d_in[7];
    const float* w1_l0 = (const float*)d_in[8];
    const float* u3_l1 = (const float*)d_in[9];
    const float* u2_l1 = (const float*)d_in[10];
    const float* u1_l1 = (const float*)d_in[11];
    const float* w3_l1 = (const float*)d_in[12];
    const float* w2_l1 = (const float*)d_in[13];
    const float* w1_l1 = (const float*)d_in[14];
    const float* lw0   = (const float*)d_in[15];
    const float* lw1   = (const float*)d_in[16];
    float* out = (float*)d_out;

    // Workspace: Utab (f16, 14336 B) | us1f (fp32, 288 B)
    _Float16* Utab = (_Float16*)d_ws;
    float* us1f = (float*)((char*)d_ws + UTAB_HALVES * 2);

    build_utab_kernel<<<(UTAB_HALVES + 72 + 255) / 256, 256, 0, stream>>>(
        u3_l0, u2_l0, u1_l0, u3_l1, u2_l1, u1_l1, Utab, us1f);
    fused_kernel<<<N_NODES / 2, 256, 0, stream>>>(
        x, y, Utab, us1f,
        w3_l0, w2_l0, w1_l0, w3_l1, w2_l1, w1_l1,
        lw0, lw1, sc, out);
}